// Round 4
// baseline (45347.833 us; speedup 1.0000x reference)
//
#include <hip/hip_runtime.h>
#include <hip/hip_bf16.h>

// Problem constants
#define BB 32     // batch
#define TT 512    // time
#define AA 512    // acoustic dim
#define EE 256    // emb dim
#define HH 320    // hidden
#define VV 8192   // vocab
#define KIN 768   // A+E
#define G4 1280   // 4*H

#define NBLK 5    // blocks per batch (recurrence)
#define UPB 64    // hidden units per block
#define KS 80     // k-chunk per lane-group

typedef __bf16 bf16x8v __attribute__((ext_vector_type(8)));
typedef float f32x4 __attribute__((ext_vector_type(4)));

__device__ __forceinline__ float sigm(float x) { return 1.f / (1.f + expf(-x)); }
__device__ __forceinline__ unsigned short f2bf(float f) {
    __hip_bfloat16 h = __float2bfloat16(f);
    return *(unsigned short*)&h;
}

// ---------------- Stage A: X[r=t*B+b][j] = tanh(concat(a,e) . W_in[j,:] + b_in[j]) ----------------
__global__ __launch_bounds__(320) void stage_x(const float* __restrict__ ac,
                                               const int* __restrict__ tok,
                                               const float* __restrict__ emb,
                                               const float* __restrict__ Win,
                                               const float* __restrict__ bin,
                                               float* __restrict__ X) {
    __shared__ float xs[8][KIN];
    const int r0 = blockIdx.x * 8;
    const int tid = threadIdx.x;
    for (int rr = 0; rr < 8; ++rr) {
        const int r = r0 + rr;
        const int t = r >> 5;
        const int b = r & 31;
        const int tk = tok[b * TT + t];
        const float4* ac4  = (const float4*)(ac + ((size_t)b * TT + t) * AA);
        const float4* emb4 = (const float4*)(emb + (size_t)tk * EE);
        float4* xs4 = (float4*)&xs[rr][0];
        for (int k4 = tid; k4 < KIN / 4; k4 += 320) {
            float4 v;
            if (k4 < AA / 4) v = ac4[k4];
            else if (tk == 0) v = make_float4(0.f, 0.f, 0.f, 0.f);
            else v = emb4[k4 - AA / 4];
            xs4[k4] = v;
        }
    }
    __syncthreads();
    const int j = tid;
    float acc[8];
    const float bj = bin[j];
#pragma unroll
    for (int rr = 0; rr < 8; ++rr) acc[rr] = bj;
    const float4* w4 = (const float4*)(Win + (size_t)j * KIN);
#pragma unroll 4
    for (int k4 = 0; k4 < KIN / 4; ++k4) {
        const float4 wv = w4[k4];
#pragma unroll
        for (int rr = 0; rr < 8; ++rr) {
            const float4 xv = ((const float4*)&xs[rr][0])[k4];
            acc[rr] += wv.x * xv.x + wv.y * xv.y + wv.z * xv.z + wv.w * xv.w;
        }
    }
#pragma unroll
    for (int rr = 0; rr < 8; ++rr)
        X[(size_t)(r0 + rr) * HH + j] = tanhf(acc[rr]);
}

// ---------------- Stage B: G[r][j] = X[r,:] . W_ih[j,:] + b_ih[j] + b_hh[j] ----------------
__global__ __launch_bounds__(256) void stage_gin(const float* __restrict__ X,
                                                 const float* __restrict__ Wih,
                                                 const float* __restrict__ bih,
                                                 const float* __restrict__ bhh,
                                                 float* __restrict__ G) {
    __shared__ float xs[8][HH];
    const int r0 = blockIdx.x * 8;
    const int tid = threadIdx.x;
    {
        const float4* src = (const float4*)(X + (size_t)r0 * HH);
        float4* dst = (float4*)&xs[0][0];
        for (int k4 = tid; k4 < 8 * HH / 4; k4 += 256) dst[k4] = src[k4];
    }
    __syncthreads();
    for (int p = 0; p < 5; ++p) {
        const int j = tid + 256 * p;
        const float bias = bih[j] + bhh[j];
        float acc[8];
#pragma unroll
        for (int rr = 0; rr < 8; ++rr) acc[rr] = bias;
        const float4* w4 = (const float4*)(Wih + (size_t)j * HH);
#pragma unroll 4
        for (int k4 = 0; k4 < HH / 4; ++k4) {
            const float4 wv = w4[k4];
#pragma unroll
            for (int rr = 0; rr < 8; ++rr) {
                const float4 xv = ((const float4*)&xs[rr][0])[k4];
                acc[rr] += wv.x * xv.x + wv.y * xv.y + wv.z * xv.z + wv.w * xv.w;
            }
        }
#pragma unroll
        for (int rr = 0; rr < 8; ++rr)
            G[(size_t)(r0 + rr) * G4 + j] = acc[rr];
    }
}

// ---------------- Wout fp32 -> bf16 ----------------
__global__ __launch_bounds__(256) void wcvt(const float* __restrict__ src,
                                            unsigned short* __restrict__ dst, int n4) {
    const int i = blockIdx.x * 256 + threadIdx.x;
    if (i < n4) {
        const float4 v = ((const float4*)src)[i];
        ushort4 o;
        o.x = f2bf(v.x); o.y = f2bf(v.y); o.z = f2bf(v.z); o.w = f2bf(v.w);
        ((ushort4*)dst)[i] = o;
    }
}

// ---------------- Stage C: LSTM recurrence ----------------
// Grid 160 = 8 XCD-residues x 20. bid -> (b,p) s.t. all 5 blocks of batch b share bid%8
// (co-located on one XCD under round-robin dispatch; perf heuristic only).
// Thread (wave w, lane l): gate-row r = w*16 + (l&15) in [0,256); k-chunk g = l>>4.
// Whh row-chunk (80 floats) pinned in VGPRs. Row reduction = 2 x shfl_xor.
// One __syncthreads per step; cross-block sync via per-batch counter in L2.
__global__ __launch_bounds__(1024, 4) void stage_rec(const float* __restrict__ G,
                                                     const float* __restrict__ Whh,
                                                     unsigned short* __restrict__ Hsb,
                                                     float* __restrict__ hbuf,   // [2][BB][HH]
                                                     int* __restrict__ cnt) {    // [BB*32]
    const int bid = blockIdx.x;
    const int xres = bid & 7;
    const int inner = bid >> 3;
    const int b = (inner / NBLK) * 8 + xres;
    const int p = inner % NBLK;
    const int U0 = p * UPB;
    const int tid = threadIdx.x;
    const int l = tid & 63;
    const int w = tid >> 6;
    const int lr = l & 15;
    const int g = l >> 4;                 // k-chunk 0..3
    const int r = w * 16 + lr;            // slice gate-row 0..255
    const int q = r >> 6;                 // gate 0..3
    const int u = r & 63;                 // unit within slice
    const int j = q * HH + U0 + u;        // global gate row

    __shared__ float gates[256];

    // pin Whh[j][g*80 .. +80) in 20 float4 VGPRs
    float4 wv[20];
    {
        const float4* wp = (const float4*)(Whh + (size_t)j * HH + g * KS);
#pragma unroll
        for (int i = 0; i < 20; ++i) wv[i] = wp[i];
#pragma unroll
        for (int i = 0; i < 20; ++i)
            asm volatile("" : "+v"(wv[i].x), "+v"(wv[i].y), "+v"(wv[i].z), "+v"(wv[i].w));
    }
    float c_reg = 0.f;                    // live in wave 0 (tid<64), unit u=tid
    int* cnt_b = cnt + b * 32;

    for (int t = 0; t < TT; ++t) {
        const float gin = G[((size_t)t * BB + b) * G4 + j];
        float acc = 0.f;
        if (t > 0) {
            const int target = NBLK * t;
            while (__hip_atomic_load(cnt_b, __ATOMIC_RELAXED, __HIP_MEMORY_SCOPE_AGENT) < target)
                __builtin_amdgcn_s_sleep(1);
            __threadfence();   // acquire
            const float4* h4 = (const float4*)(hbuf + ((size_t)(t & 1) * BB + b) * HH + g * KS);
#pragma unroll 4
            for (int i = 0; i < 20; ++i) {
                const float4 hv = h4[i];
                acc += wv[i].x * hv.x + wv[i].y * hv.y + wv[i].z * hv.z + wv[i].w * hv.w;
            }
            acc += __shfl_xor(acc, 16, 64);
            acc += __shfl_xor(acc, 32, 64);
        }
        if (l < 16) gates[r] = acc + gin;
        __syncthreads();
        if (tid < UPB) {
            const float gi = gates[tid];
            const float gf = gates[64 + tid];
            const float gg = gates[128 + tid];
            const float go = gates[192 + tid];
            const float cn = sigm(gf) * c_reg + sigm(gi) * tanhf(gg);
            const float hn = sigm(go) * tanhf(cn);
            c_reg = cn;
            Hsb[((size_t)b * TT + t) * HH + U0 + tid] = f2bf(hn);
            hbuf[((size_t)((t + 1) & 1) * BB + b) * HH + U0 + tid] = hn;
        }
        if (tid == 0) {
            __threadfence();   // release: wave-0's hbuf stores drain before bump
            __hip_atomic_fetch_add(cnt_b, 1, __ATOMIC_RELAXED, __HIP_MEMORY_SCOPE_AGENT);
        }
    }
}

// ---------------- Stage D: MFMA bf16 GEMM: out[m][v] = Hsb[m,:] . Woutb[v,:] + bout[v] ----------------
// 128x128 tile, 4 waves (2x2), 4x4 fragments of 16x16x32 each, K=320 (10 steps).
__global__ __launch_bounds__(256, 2) void stage_logits_mfma(const unsigned short* __restrict__ A,
                                                            const unsigned short* __restrict__ Bm,
                                                            const float* __restrict__ bout,
                                                            float* __restrict__ out) {
    __shared__ unsigned short As[128][40];   // +8 pad: 80B row stride, 16B-aligned
    __shared__ unsigned short Bs[128][40];
    const int tid = threadIdx.x;
    const int m0 = blockIdx.y * 128;
    const int n0 = blockIdx.x * 128;
    const int w = tid >> 6, l = tid & 63;
    const int wr = w >> 1, wc = w & 1;
    const int lr = l & 15, lk = l >> 4;

    f32x4 acc[4][4] = {};
    for (int k0 = 0; k0 < HH; k0 += 32) {
#pragma unroll
        for (int i = 0; i < 2; ++i) {
            const int uidx = tid + 256 * i;
            const int rr = uidx >> 2, ss = uidx & 3;
            *(uint4*)&As[rr][ss * 8] = *(const uint4*)(A + (size_t)(m0 + rr) * HH + k0 + ss * 8);
            *(uint4*)&Bs[rr][ss * 8] = *(const uint4*)(Bm + (size_t)(n0 + rr) * HH + k0 + ss * 8);
        }
        __syncthreads();
        bf16x8v af[4], bfr[4];
#pragma unroll
        for (int f = 0; f < 4; ++f) {
            af[f]  = *(const bf16x8v*)&As[wr * 64 + f * 16 + lr][lk * 8];
            bfr[f] = *(const bf16x8v*)&Bs[wc * 64 + f * 16 + lr][lk * 8];
        }
#pragma unroll
        for (int fm = 0; fm < 4; ++fm)
#pragma unroll
            for (int fn = 0; fn < 4; ++fn)
                acc[fm][fn] = __builtin_amdgcn_mfma_f32_16x16x32_bf16(af[fm], bfr[fn], acc[fm][fn], 0, 0, 0);
        __syncthreads();
    }
#pragma unroll
    for (int fn = 0; fn < 4; ++fn) {
        const int n = n0 + wc * 64 + fn * 16 + lr;
        const float bv = bout[n];
#pragma unroll
        for (int fm = 0; fm < 4; ++fm) {
            const int mbase = m0 + wr * 64 + fm * 16 + lk * 4;
#pragma unroll
            for (int rg = 0; rg < 4; ++rg)
                out[(size_t)(mbase + rg) * VV + n] = acc[fm][fn][rg] + bv;
        }
    }
}

// ---------------- Stage E: in-place log_softmax over V per row ----------------
__global__ __launch_bounds__(256) void stage_lsm(float* __restrict__ out) {
    __shared__ float buf[VV];
    __shared__ float red[16];
    const size_t m = blockIdx.x;
    float4* row4 = (float4*)(out + m * VV);
    float4* buf4 = (float4*)buf;
    const int tid = threadIdx.x;

    float mx = -INFINITY;
    for (int k4 = tid; k4 < VV / 4; k4 += 256) {
        const float4 v = row4[k4];
        buf4[k4] = v;
        mx = fmaxf(mx, fmaxf(fmaxf(v.x, v.y), fmaxf(v.z, v.w)));
    }
#pragma unroll
    for (int off = 32; off > 0; off >>= 1) mx = fmaxf(mx, __shfl_down(mx, off, 64));
    if ((tid & 63) == 0) red[tid >> 6] = mx;
    __syncthreads();
    if (tid == 0) {
        float m2 = red[0];
        for (int i = 1; i < 4; ++i) m2 = fmaxf(m2, red[i]);
        red[0] = m2;
    }
    __syncthreads();
    mx = red[0];

    float s = 0.f;
    for (int k4 = tid; k4 < VV / 4; k4 += 256) {
        const float4 v = buf4[k4];
        s += expf(v.x - mx) + expf(v.y - mx) + expf(v.z - mx) + expf(v.w - mx);
    }
#pragma unroll
    for (int off = 32; off > 0; off >>= 1) s += __shfl_down(s, off, 64);
    if ((tid & 63) == 0) red[8 + (tid >> 6)] = s;
    __syncthreads();
    if (tid == 0) {
        float s2 = 0.f;
        for (int i = 0; i < 4; ++i) s2 += red[8 + i];
        red[8] = logf(s2);
    }
    __syncthreads();
    const float lse = mx + red[8];
    for (int k4 = tid; k4 < VV / 4; k4 += 256) {
        float4 v = buf4[k4];
        v.x -= lse; v.y -= lse; v.z -= lse; v.w -= lse;
        row4[k4] = v;
    }
}

extern "C" void kernel_launch(void* const* d_in, const int* in_sizes, int n_in,
                              void* d_out, int out_size, void* d_ws, size_t ws_size,
                              hipStream_t stream) {
    const float* ac   = (const float*)d_in[0];
    const int*   tok  = (const int*)d_in[1];
    const float* emb  = (const float*)d_in[2];
    const float* Win  = (const float*)d_in[3];
    const float* bin  = (const float*)d_in[4];
    const float* Wih  = (const float*)d_in[5];
    const float* Whh  = (const float*)d_in[6];
    const float* bih  = (const float*)d_in[7];
    const float* bhh  = (const float*)d_in[8];
    const float* Wout = (const float*)d_in[9];
    const float* bout = (const float*)d_in[10];
    float* out = (float*)d_out;

    float* X  = (float*)d_ws;                                   // 21 MB (dead after stage_gin)
    float* G  = X + (size_t)TT * BB * HH;                       // 84 MB
    unsigned short* Hsb   = (unsigned short*)(G + (size_t)TT * BB * G4);  // 10.5 MB bf16
    unsigned short* Woutb = Hsb + (size_t)TT * BB * HH;         // 5.2 MB bf16
    // alias X (free after stage_gin):
    float* hbuf = X;                                            // [2][BB][HH]
    int*   cnt  = (int*)(X + 2 * BB * HH);                      // [BB*32]

    stage_x<<<dim3(TT * BB / 8), dim3(320), 0, stream>>>(ac, tok, emb, Win, bin, X);
    stage_gin<<<dim3(TT * BB / 8), dim3(256), 0, stream>>>(X, Wih, bih, bhh, G);
    wcvt<<<dim3((VV * HH / 4 + 255) / 256), dim3(256), 0, stream>>>(Wout, Woutb, VV * HH / 4);
    hipMemsetAsync(cnt, 0, BB * 32 * sizeof(int), stream);
    stage_rec<<<dim3(BB * NBLK), dim3(1024), 0, stream>>>(G, Whh, Hsb, hbuf, cnt);
    stage_logits_mfma<<<dim3(VV / 128, TT * BB / 128), dim3(256), 0, stream>>>(Hsb, Woutb, bout, out);
    stage_lsm<<<dim3(TT * BB), dim3(256), 0, stream>>>(out);
}

// Round 5
// 23299.551 us; speedup vs baseline: 1.9463x; 1.9463x over previous
//
#include <hip/hip_runtime.h>
#include <hip/hip_bf16.h>

// Problem constants
#define BB 32     // batch
#define TT 512    // time
#define AA 512    // acoustic dim
#define EE 256    // emb dim
#define HH 320    // hidden
#define VV 8192   // vocab
#define KIN 768   // A+E
#define G4 1280   // 4*H

#define NBLK 8    // blocks per batch (recurrence)
#define UPB 40    // hidden units per block
#define RPB 160   // gate rows per block (4*UPB)
#define KS 80     // k-chunk per lane-group (320/4)
#define RTHR 640  // threads in stage_rec

typedef __bf16 bf16x8v __attribute__((ext_vector_type(8)));
typedef float f32x4 __attribute__((ext_vector_type(4)));

__device__ __forceinline__ float sigm(float x) { return 1.f / (1.f + expf(-x)); }
__device__ __forceinline__ unsigned short f2bf(float f) {
    __hip_bfloat16 h = __float2bfloat16(f);
    return *(unsigned short*)&h;
}

// ---------------- Stage A: X[r=t*B+b][j] = tanh(concat(a,e) . W_in[j,:] + b_in[j]) ----------------
__global__ __launch_bounds__(320) void stage_x(const float* __restrict__ ac,
                                               const int* __restrict__ tok,
                                               const float* __restrict__ emb,
                                               const float* __restrict__ Win,
                                               const float* __restrict__ bin,
                                               float* __restrict__ X) {
    __shared__ float xs[8][KIN];
    const int r0 = blockIdx.x * 8;
    const int tid = threadIdx.x;
    for (int rr = 0; rr < 8; ++rr) {
        const int r = r0 + rr;
        const int t = r >> 5;
        const int b = r & 31;
        const int tk = tok[b * TT + t];
        const float4* ac4  = (const float4*)(ac + ((size_t)b * TT + t) * AA);
        const float4* emb4 = (const float4*)(emb + (size_t)tk * EE);
        float4* xs4 = (float4*)&xs[rr][0];
        for (int k4 = tid; k4 < KIN / 4; k4 += 320) {
            float4 v;
            if (k4 < AA / 4) v = ac4[k4];
            else if (tk == 0) v = make_float4(0.f, 0.f, 0.f, 0.f);
            else v = emb4[k4 - AA / 4];
            xs4[k4] = v;
        }
    }
    __syncthreads();
    const int j = tid;
    float acc[8];
    const float bj = bin[j];
#pragma unroll
    for (int rr = 0; rr < 8; ++rr) acc[rr] = bj;
    const float4* w4 = (const float4*)(Win + (size_t)j * KIN);
#pragma unroll 4
    for (int k4 = 0; k4 < KIN / 4; ++k4) {
        const float4 wv = w4[k4];
#pragma unroll
        for (int rr = 0; rr < 8; ++rr) {
            const float4 xv = ((const float4*)&xs[rr][0])[k4];
            acc[rr] += wv.x * xv.x + wv.y * xv.y + wv.z * xv.z + wv.w * xv.w;
        }
    }
#pragma unroll
    for (int rr = 0; rr < 8; ++rr)
        X[(size_t)(r0 + rr) * HH + j] = tanhf(acc[rr]);
}

// ---------------- Stage B: Gp[(R*8+p)*160 + q*40+u] = X[R,:] . W_ih[j,:] + b_ih[j] + b_hh[j] ----------------
// (permuted layout so stage_rec block (b,p) reads a contiguous 640B gin row)
__global__ __launch_bounds__(256) void stage_gin(const float* __restrict__ X,
                                                 const float* __restrict__ Wih,
                                                 const float* __restrict__ bih,
                                                 const float* __restrict__ bhh,
                                                 float* __restrict__ Gp) {
    __shared__ float xs[8][HH];
    const int r0 = blockIdx.x * 8;
    const int tid = threadIdx.x;
    {
        const float4* src = (const float4*)(X + (size_t)r0 * HH);
        float4* dst = (float4*)&xs[0][0];
        for (int k4 = tid; k4 < 8 * HH / 4; k4 += 256) dst[k4] = src[k4];
    }
    __syncthreads();
    for (int p5 = 0; p5 < 5; ++p5) {
        const int j = tid + 256 * p5;   // 0..1279
        const float bias = bih[j] + bhh[j];
        float acc[8];
#pragma unroll
        for (int rr = 0; rr < 8; ++rr) acc[rr] = bias;
        const float4* w4 = (const float4*)(Wih + (size_t)j * HH);
#pragma unroll 4
        for (int k4 = 0; k4 < HH / 4; ++k4) {
            const float4 wv = w4[k4];
#pragma unroll
            for (int rr = 0; rr < 8; ++rr) {
                const float4 xv = ((const float4*)&xs[rr][0])[k4];
                acc[rr] += wv.x * xv.x + wv.y * xv.y + wv.z * xv.z + wv.w * xv.w;
            }
        }
        const int q = j / HH;
        const int hi = j % HH;
        const int pp = hi / UPB;
        const int uu = hi % UPB;
        const int col = pp * RPB + q * UPB + uu;   // position within row's 1280 block
#pragma unroll
        for (int rr = 0; rr < 8; ++rr)
            Gp[(size_t)(r0 + rr) * G4 + col] = acc[rr];
    }
}

// ---------------- Wout fp32 -> bf16 ----------------
__global__ __launch_bounds__(256) void wcvt(const float* __restrict__ src,
                                            unsigned short* __restrict__ dst, int n4) {
    const int i = blockIdx.x * 256 + threadIdx.x;
    if (i < n4) {
        const float4 v = ((const float4*)src)[i];
        ushort4 o;
        o.x = f2bf(v.x); o.y = f2bf(v.y); o.z = f2bf(v.z); o.w = f2bf(v.w);
        ((ushort4*)dst)[i] = o;
    }
}

// ---------------- Stage C: LSTM recurrence, 8 blocks/batch, Whh bf16 in LDS ----------------
// Grid 256 (= CU count; LDS-pinned 1 block/CU -> all resident, deadlock-safe).
// bid -> (b,p): all 8 blocks of batch b share bid%8 (XCD co-location heuristic).
// Thread: row r = tid>>2 (0..159: q=r/40 gate, u=r%40 unit), k-chunk g = tid&3.
// Weight LDS XOR-swizzled (byte ^= (row&7)<<4) to kill bank conflicts.
// Per step: poll counter (is the inter-block sync), 1 __syncthreads (gates).
__global__ __launch_bounds__(RTHR) void stage_rec(const float* __restrict__ Gp,
                                                  const float* __restrict__ Whh,
                                                  unsigned short* __restrict__ Hsb,
                                                  float* __restrict__ hbuf,   // [2][BB][HH] fp32
                                                  int* __restrict__ cnt) {    // [BB*32]
    const int bid = blockIdx.x;
    const int xres = bid & 7;
    const int inner = bid >> 3;     // 0..31
    const int p = inner & 7;        // slice 0..7
    const int b = (inner >> 3) * 8 + xres;  // batch 0..31
    const int tid = threadIdx.x;
    const int r = tid >> 2;         // 0..159
    const int g = tid & 3;          // 0..3
    const int q = r / UPB;          // gate 0..3
    const int u = r - q * UPB;      // unit 0..39
    const int j = q * HH + p * UPB + u;   // global Whh row

    __shared__ unsigned char wlds[RPB * 640];   // bf16 [160][320], XOR-swizzled
    __shared__ float gates[2][RPB];

    // one-time: load fp32 Whh slice, convert to bf16, store swizzled
    for (int idx = tid; idx < RPB * 40; idx += RTHR) {   // 40 16B-slots per row
        const int rr = idx / 40, s = idx - (idx / 40) * 40;
        const int qq = rr / UPB, uu = rr - qq * UPB;
        const int jj = qq * HH + p * UPB + uu;
        const float4 v0 = *(const float4*)(Whh + (size_t)jj * HH + s * 8);
        const float4 v1 = *(const float4*)(Whh + (size_t)jj * HH + s * 8 + 4);
        unsigned char* dst = wlds + rr * 640 + ((s * 16) ^ ((rr & 7) << 4));
        ushort4 o0 = { f2bf(v0.x), f2bf(v0.y), f2bf(v0.z), f2bf(v0.w) };
        ushort4 o1 = { f2bf(v1.x), f2bf(v1.y), f2bf(v1.z), f2bf(v1.w) };
        *(ushort4*)dst = o0;
        *(ushort4*)(dst + 8) = o1;
    }
    __syncthreads();

    float c_reg = 0.f;              // valid for tid < UPB (wave 0)
    int* cnt_b = cnt + b * 32;
    const unsigned char* wrow = wlds + r * 640;
    const int rx = (r & 7) << 4;

    for (int t = 0; t < TT; ++t) {
        // gin load (writer lanes) issues before the poll; independent of sync
        float gin = 0.f;
        if (g == 0) gin = Gp[(size_t)(t * BB + b) * G4 + p * RPB + r];
        float acc = 0.f;
        if (t > 0) {
            const int target = NBLK * t;
            while (__hip_atomic_load(cnt_b, __ATOMIC_RELAXED, __HIP_MEMORY_SCOPE_AGENT) < target)
                __builtin_amdgcn_s_sleep(1);
            __threadfence();        // acquire
            const float4* h4 = (const float4*)(hbuf + ((size_t)(t & 1) * BB + b) * HH + g * KS);
#pragma unroll
            for (int i = 0; i < 10; ++i) {
                const bf16x8v w8 = *(const bf16x8v*)(wrow + (((g * 10 + i) * 16) ^ rx));
                const float4 ha = h4[2 * i];
                const float4 hb = h4[2 * i + 1];
                acc += (float)w8[0] * ha.x + (float)w8[1] * ha.y +
                       (float)w8[2] * ha.z + (float)w8[3] * ha.w;
                acc += (float)w8[4] * hb.x + (float)w8[5] * hb.y +
                       (float)w8[6] * hb.z + (float)w8[7] * hb.w;
            }
            acc += __shfl_xor(acc, 1, 64);
            acc += __shfl_xor(acc, 2, 64);
        }
        if (g == 0) gates[t & 1][r] = acc + gin;
        __syncthreads();
        if (tid < UPB) {
            const float gi = gates[t & 1][tid];
            const float gf = gates[t & 1][UPB + tid];
            const float gg = gates[t & 1][2 * UPB + tid];
            const float go = gates[t & 1][3 * UPB + tid];
            const float cn = sigm(gf) * c_reg + sigm(gi) * tanhf(gg);
            const float hn = sigm(go) * tanhf(cn);
            c_reg = cn;
            Hsb[((size_t)b * TT + t) * HH + p * UPB + tid] = f2bf(hn);
            hbuf[((size_t)((t + 1) & 1) * BB + b) * HH + p * UPB + tid] = hn;
        }
        if (tid == 0) {
            __threadfence();        // release: wave-0 h stores drain before bump
            __hip_atomic_fetch_add(cnt_b, 1, __ATOMIC_RELAXED, __HIP_MEMORY_SCOPE_AGENT);
        }
        // no 2nd barrier: gates ping-pong + counter poll protect WAR hazards
    }
}

// ---------------- Stage D: MFMA bf16 GEMM: out[m][v] = Hsb[m,:] . Woutb[v,:] + bout[v] ----------------
__global__ __launch_bounds__(256, 2) void stage_logits_mfma(const unsigned short* __restrict__ A,
                                                            const unsigned short* __restrict__ Bm,
                                                            const float* __restrict__ bout,
                                                            float* __restrict__ out) {
    __shared__ unsigned short As[128][40];
    __shared__ unsigned short Bs[128][40];
    const int tid = threadIdx.x;
    const int m0 = blockIdx.y * 128;
    const int n0 = blockIdx.x * 128;
    const int w = tid >> 6, l = tid & 63;
    const int wr = w >> 1, wc = w & 1;
    const int lr = l & 15, lk = l >> 4;

    f32x4 acc[4][4] = {};
    for (int k0 = 0; k0 < HH; k0 += 32) {
#pragma unroll
        for (int i = 0; i < 2; ++i) {
            const int uidx = tid + 256 * i;
            const int rr = uidx >> 2, ss = uidx & 3;
            *(uint4*)&As[rr][ss * 8] = *(const uint4*)(A + (size_t)(m0 + rr) * HH + k0 + ss * 8);
            *(uint4*)&Bs[rr][ss * 8] = *(const uint4*)(Bm + (size_t)(n0 + rr) * HH + k0 + ss * 8);
        }
        __syncthreads();
        bf16x8v af[4], bfr[4];
#pragma unroll
        for (int f = 0; f < 4; ++f) {
            af[f]  = *(const bf16x8v*)&As[wr * 64 + f * 16 + lr][lk * 8];
            bfr[f] = *(const bf16x8v*)&Bs[wc * 64 + f * 16 + lr][lk * 8];
        }
#pragma unroll
        for (int fm = 0; fm < 4; ++fm)
#pragma unroll
            for (int fn = 0; fn < 4; ++fn)
                acc[fm][fn] = __builtin_amdgcn_mfma_f32_16x16x32_bf16(af[fm], bfr[fn], acc[fm][fn], 0, 0, 0);
        __syncthreads();
    }
#pragma unroll
    for (int fn = 0; fn < 4; ++fn) {
        const int n = n0 + wc * 64 + fn * 16 + lr;
        const float bv = bout[n];
#pragma unroll
        for (int fm = 0; fm < 4; ++fm) {
            const int mbase = m0 + wr * 64 + fm * 16 + lk * 4;
#pragma unroll
            for (int rg = 0; rg < 4; ++rg)
                out[(size_t)(mbase + rg) * VV + n] = acc[fm][fn][rg] + bv;
        }
    }
}

// ---------------- Stage E: in-place log_softmax over V per row ----------------
__global__ __launch_bounds__(256) void stage_lsm(float* __restrict__ out) {
    __shared__ float buf[VV];
    __shared__ float red[16];
    const size_t m = blockIdx.x;
    float4* row4 = (float4*)(out + m * VV);
    float4* buf4 = (float4*)buf;
    const int tid = threadIdx.x;

    float mx = -INFINITY;
    for (int k4 = tid; k4 < VV / 4; k4 += 256) {
        const float4 v = row4[k4];
        buf4[k4] = v;
        mx = fmaxf(mx, fmaxf(fmaxf(v.x, v.y), fmaxf(v.z, v.w)));
    }
#pragma unroll
    for (int off = 32; off > 0; off >>= 1) mx = fmaxf(mx, __shfl_down(mx, off, 64));
    if ((tid & 63) == 0) red[tid >> 6] = mx;
    __syncthreads();
    if (tid == 0) {
        float m2 = red[0];
        for (int i = 1; i < 4; ++i) m2 = fmaxf(m2, red[i]);
        red[0] = m2;
    }
    __syncthreads();
    mx = red[0];

    float s = 0.f;
    for (int k4 = tid; k4 < VV / 4; k4 += 256) {
        const float4 v = buf4[k4];
        s += expf(v.x - mx) + expf(v.y - mx) + expf(v.z - mx) + expf(v.w - mx);
    }
#pragma unroll
    for (int off = 32; off > 0; off >>= 1) s += __shfl_down(s, off, 64);
    if ((tid & 63) == 0) red[8 + (tid >> 6)] = s;
    __syncthreads();
    if (tid == 0) {
        float s2 = 0.f;
        for (int i = 0; i < 4; ++i) s2 += red[8 + i];
        red[8] = logf(s2);
    }
    __syncthreads();
    const float lse = mx + red[8];
    for (int k4 = tid; k4 < VV / 4; k4 += 256) {
        float4 v = buf4[k4];
        v.x -= lse; v.y -= lse; v.z -= lse; v.w -= lse;
        row4[k4] = v;
    }
}

extern "C" void kernel_launch(void* const* d_in, const int* in_sizes, int n_in,
                              void* d_out, int out_size, void* d_ws, size_t ws_size,
                              hipStream_t stream) {
    const float* ac   = (const float*)d_in[0];
    const int*   tok  = (const int*)d_in[1];
    const float* emb  = (const float*)d_in[2];
    const float* Win  = (const float*)d_in[3];
    const float* bin  = (const float*)d_in[4];
    const float* Wih  = (const float*)d_in[5];
    const float* Whh  = (const float*)d_in[6];
    const float* bih  = (const float*)d_in[7];
    const float* bhh  = (const float*)d_in[8];
    const float* Wout = (const float*)d_in[9];
    const float* bout = (const float*)d_in[10];
    float* out = (float*)d_out;

    float* X  = (float*)d_ws;                                   // [T*B,H] fp32, 21 MB
    float* Gp = X + (size_t)TT * BB * HH;                       // [T*B,4H] permuted, 84 MB
    unsigned short* Hsb   = (unsigned short*)(Gp + (size_t)TT * BB * G4);  // 10.5 MB
    unsigned short* Woutb = Hsb + (size_t)TT * BB * HH;         // 5.2 MB
    float* hbuf = (float*)(Woutb + (size_t)VV * HH);            // [2][BB][HH] 80 KB
    int*   cnt  = (int*)(hbuf + 2 * BB * HH);                   // [BB*32] 4 KB

    stage_x<<<dim3(TT * BB / 8), dim3(320), 0, stream>>>(ac, tok, emb, Win, bin, X);
    stage_gin<<<dim3(TT * BB / 8), dim3(256), 0, stream>>>(X, Wih, bih, bhh, Gp);
    wcvt<<<dim3((VV * HH / 4 + 255) / 256), dim3(256), 0, stream>>>(Wout, Woutb, VV * HH / 4);
    hipMemsetAsync(cnt, 0, BB * 32 * sizeof(int), stream);
    stage_rec<<<dim3(BB * NBLK), dim3(RTHR), 0, stream>>>(Gp, Whh, Hsb, hbuf, cnt);
    stage_logits_mfma<<<dim3(VV / 128, TT * BB / 128), dim3(256), 0, stream>>>(Hsb, Woutb, bout, out);
    stage_lsm<<<dim3(TT * BB), dim3(256), 0, stream>>>(out);
}

// Round 6
// 5281.479 us; speedup vs baseline: 8.5862x; 4.4116x over previous
//
#include <hip/hip_runtime.h>
#include <hip/hip_bf16.h>

// Problem constants
#define BB 32     // batch
#define TT 512    // time
#define AA 512    // acoustic dim
#define EE 256    // emb dim
#define HH 320    // hidden
#define VV 8192   // vocab
#define KIN 768   // A+E
#define G4 1280   // 4*H

#define NBLK 8    // recurrence blocks (total, ONE sync group)
#define UPB 40    // hidden units per block
#define RPB 160   // gate rows per block
#define RTHR 640  // threads in stage_rec (10 waves)
#define WPAD 328  // padded bf16 row length (+8 => +16B: conflict-free frag reads)
#define GLP 161   // gates LDS row pad (odd => distinct banks across m)

typedef __bf16 bf16x8v __attribute__((ext_vector_type(8)));
typedef float f32x4 __attribute__((ext_vector_type(4)));

__device__ __forceinline__ float fexp(float x) { return __expf(x); }
__device__ __forceinline__ float fsigm(float x) { return 1.f / (1.f + __expf(-x)); }
__device__ __forceinline__ float ftanh(float x) { return 2.f / (1.f + __expf(-2.f * x)) - 1.f; }
__device__ __forceinline__ unsigned short f2bf(float f) {
    __hip_bfloat16 h = __float2bfloat16(f);
    return *(unsigned short*)&h;
}

// ---------------- Stage A: X[r=t*B+b][j] = tanh(concat(a,e) . W_in[j,:] + b_in[j]) ----------------
__global__ __launch_bounds__(320) void stage_x(const float* __restrict__ ac,
                                               const int* __restrict__ tok,
                                               const float* __restrict__ emb,
                                               const float* __restrict__ Win,
                                               const float* __restrict__ bin,
                                               float* __restrict__ X) {
    __shared__ float xs[8][KIN];
    const int r0 = blockIdx.x * 8;
    const int tid = threadIdx.x;
    for (int rr = 0; rr < 8; ++rr) {
        const int r = r0 + rr;
        const int t = r >> 5;
        const int b = r & 31;
        const int tk = tok[b * TT + t];
        const float4* ac4  = (const float4*)(ac + ((size_t)b * TT + t) * AA);
        const float4* emb4 = (const float4*)(emb + (size_t)tk * EE);
        float4* xs4 = (float4*)&xs[rr][0];
        for (int k4 = tid; k4 < KIN / 4; k4 += 320) {
            float4 v;
            if (k4 < AA / 4) v = ac4[k4];
            else if (tk == 0) v = make_float4(0.f, 0.f, 0.f, 0.f);
            else v = emb4[k4 - AA / 4];
            xs4[k4] = v;
        }
    }
    __syncthreads();
    const int j = tid;
    float acc[8];
    const float bj = bin[j];
#pragma unroll
    for (int rr = 0; rr < 8; ++rr) acc[rr] = bj;
    const float4* w4 = (const float4*)(Win + (size_t)j * KIN);
#pragma unroll 4
    for (int k4 = 0; k4 < KIN / 4; ++k4) {
        const float4 wv = w4[k4];
#pragma unroll
        for (int rr = 0; rr < 8; ++rr) {
            const float4 xv = ((const float4*)&xs[rr][0])[k4];
            acc[rr] += wv.x * xv.x + wv.y * xv.y + wv.z * xv.z + wv.w * xv.w;
        }
    }
#pragma unroll
    for (int rr = 0; rr < 8; ++rr)
        X[(size_t)(r0 + rr) * HH + j] = tanhf(acc[rr]);
}

// ---------------- Stage B: Gp[(((t*8+p)*4+q)*40+u)*32 + b] = X[r,:] . W_ih[j,:] + biases ----------------
__global__ __launch_bounds__(256) void stage_gin(const float* __restrict__ X,
                                                 const float* __restrict__ Wih,
                                                 const float* __restrict__ bih,
                                                 const float* __restrict__ bhh,
                                                 float* __restrict__ Gp) {
    __shared__ float xs[8][HH];
    const int r0 = blockIdx.x * 8;
    const int tid = threadIdx.x;
    {
        const float4* src = (const float4*)(X + (size_t)r0 * HH);
        float4* dst = (float4*)&xs[0][0];
        for (int k4 = tid; k4 < 8 * HH / 4; k4 += 256) dst[k4] = src[k4];
    }
    __syncthreads();
    const int t = r0 >> 5;          // same for all 8 rows (r0 multiple of 8)
    const int b0 = r0 & 31;
    for (int p5 = 0; p5 < 5; ++p5) {
        const int j = tid + 256 * p5;   // 0..1279
        const float bias = bih[j] + bhh[j];
        float acc[8];
#pragma unroll
        for (int rr = 0; rr < 8; ++rr) acc[rr] = bias;
        const float4* w4 = (const float4*)(Wih + (size_t)j * HH);
#pragma unroll 4
        for (int k4 = 0; k4 < HH / 4; ++k4) {
            const float4 wv = w4[k4];
#pragma unroll
            for (int rr = 0; rr < 8; ++rr) {
                const float4 xv = ((const float4*)&xs[rr][0])[k4];
                acc[rr] += wv.x * xv.x + wv.y * xv.y + wv.z * xv.z + wv.w * xv.w;
            }
        }
        const int q = j / HH;
        const int hi = j - q * HH;
        const int pp = hi / UPB;
        const int uu = hi - pp * UPB;
        float* dst = Gp + ((((size_t)t * NBLK + pp) * 4 + q) * UPB + uu) * BB + b0;
#pragma unroll
        for (int rr = 0; rr < 8; ++rr) dst[rr] = acc[rr];   // 8 consecutive b
    }
}

// ---------------- Wout fp32 -> bf16 ----------------
__global__ __launch_bounds__(256) void wcvt(const float* __restrict__ src,
                                            unsigned short* __restrict__ dst, int n4) {
    const int i = blockIdx.x * 256 + threadIdx.x;
    if (i < n4) {
        const float4 v = ((const float4*)src)[i];
        ushort4 o;
        o.x = f2bf(v.x); o.y = f2bf(v.y); o.z = f2bf(v.z); o.w = f2bf(v.w);
        ((ushort4*)dst)[i] = o;
    }
}

// ---------------- Stage C: batched MFMA recurrence, 8 blocks total ----------------
// Block p owns hidden units [p*40, p*40+40) (160 gate rows) for ALL 32 batches.
// Per step: gates[32][160] = H[32][320](bf16,LDS) @ WhhSlice^T(bf16,LDS) via MFMA,
// + Gp, cell update (c in VGPRs, 2 cells/thread), h -> global hbuf, 1 counter bump.
// Sync: ONE thread per block polls the single counter; others parked at barrier.
__global__ __launch_bounds__(RTHR) void stage_rec(const float* __restrict__ Gp,
                                                  const float* __restrict__ Whh,
                                                  unsigned short* __restrict__ Hsb,
                                                  float* __restrict__ hbuf,   // [2][BB][HH] fp32
                                                  int* __restrict__ cnt) {
    if (blockIdx.x & 7) return;           // 8 real blocks, one per bid%8 residue slot
    const int p = blockIdx.x >> 3;        // 0..7
    const int tid = threadIdx.x;
    const int l = tid & 63, w = tid >> 6; // 10 waves
    const int lr = l & 15, lk = l >> 4;

    __shared__ unsigned short Wl[RPB][WPAD];  // 105.0 KB
    __shared__ unsigned short Hl[BB][WPAD];   //  21.0 KB
    __shared__ float Gl[BB * GLP];            //  20.6 KB

    // one-time: Whh slice (rows j = q*320 + p*40 + u) -> bf16 LDS, row rr = q*40+u
    for (int idx = tid; idx < RPB * 40; idx += RTHR) {
        const int rr = idx / 40, s = idx - (idx / 40) * 40;
        const int q = rr / UPB, u = rr - (rr / UPB) * UPB;
        const float* src = Whh + (size_t)(q * HH + p * UPB + u) * HH + s * 8;
        const float4 v0 = *(const float4*)src;
        const float4 v1 = *(const float4*)(src + 4);
        unsigned short tmp[8] = { f2bf(v0.x), f2bf(v0.y), f2bf(v0.z), f2bf(v0.w),
                                  f2bf(v1.x), f2bf(v1.y), f2bf(v1.z), f2bf(v1.w) };
        *(uint4*)&Wl[rr][s * 8] = *(const uint4*)tmp;
    }
    __syncthreads();

    // cell ownership: cells cid = tid and tid+640; m = cid&31, u = cid>>5
    const int mc = tid & 31;
    const int uc0 = tid >> 5;             // 0..19
    const int uc1 = uc0 + 20;             // 20..39
    float c0 = 0.f, c1 = 0.f;
    const int mw = w & 1;                 // m-tile for MFMA
    const int np = w >> 1;                // n-pair 0..4

    for (int t = 0; t < TT; ++t) {
        // step-t gate inputs (coalesced; independent of the sync)
        const size_t gbase = ((size_t)t * NBLK + p) * 4;
        float g0[4], g1[4];
#pragma unroll
        for (int q = 0; q < 4; ++q) {
            g0[q] = Gp[((gbase + q) * UPB + uc0) * BB + mc];
            g1[q] = Gp[((gbase + q) * UPB + uc1) * BB + mc];
        }
        if (t > 0) {
            if (tid == 0) {
                while (__hip_atomic_load(cnt, __ATOMIC_RELAXED, __HIP_MEMORY_SCOPE_AGENT) < NBLK * t)
                    __builtin_amdgcn_s_sleep(1);
                __threadfence();          // acquire: invalidate stale cached h
            }
            __syncthreads();
            // stage h[32][320] fp32 -> Hl bf16 (each thread: 16 contiguous elems)
            {
                const int m = tid / 20, k0 = (tid - (tid / 20) * 20) * 16;
                const float4* src = (const float4*)(hbuf + ((size_t)(t & 1) * BB + m) * HH + k0);
                const float4 a = src[0], b2 = src[1], c2 = src[2], d2 = src[3];
                unsigned short tmp[16] = {
                    f2bf(a.x), f2bf(a.y), f2bf(a.z), f2bf(a.w),
                    f2bf(b2.x), f2bf(b2.y), f2bf(b2.z), f2bf(b2.w),
                    f2bf(c2.x), f2bf(c2.y), f2bf(c2.z), f2bf(c2.w),
                    f2bf(d2.x), f2bf(d2.y), f2bf(d2.z), f2bf(d2.w) };
                *(uint4*)&Hl[m][k0] = *(const uint4*)tmp;
                *(uint4*)&Hl[m][k0 + 8] = *(const uint4*)(tmp + 8);
            }
            __syncthreads();
            // MFMA: wave w computes m-tile mw, n-tiles {np*2, np*2+1}
            f32x4 acc0 = {}, acc1 = {};
#pragma unroll
            for (int kc = 0; kc < 10; ++kc) {
                const bf16x8v av = *(const bf16x8v*)&Hl[mw * 16 + lr][kc * 32 + lk * 8];
                const bf16x8v b0 = *(const bf16x8v*)&Wl[np * 32 + lr][kc * 32 + lk * 8];
                const bf16x8v b1 = *(const bf16x8v*)&Wl[np * 32 + 16 + lr][kc * 32 + lk * 8];
                acc0 = __builtin_amdgcn_mfma_f32_16x16x32_bf16(av, b0, acc0, 0, 0, 0);
                acc1 = __builtin_amdgcn_mfma_f32_16x16x32_bf16(av, b1, acc1, 0, 0, 0);
            }
#pragma unroll
            for (int rg = 0; rg < 4; ++rg) {
                const int m = mw * 16 + lk * 4 + rg;   // C/D: row=(lane>>4)*4+reg, col=lane&15
                Gl[m * GLP + np * 32 + lr] = acc0[rg];
                Gl[m * GLP + np * 32 + 16 + lr] = acc1[rg];
            }
            __syncthreads();
        }
        // cell update (2 cells per thread)
        {
            float a0[4], a1[4];
#pragma unroll
            for (int q = 0; q < 4; ++q) {
                a0[q] = g0[q] + (t > 0 ? Gl[mc * GLP + q * UPB + uc0] : 0.f);
                a1[q] = g1[q] + (t > 0 ? Gl[mc * GLP + q * UPB + uc1] : 0.f);
            }
            const float cn0 = fsigm(a0[1]) * c0 + fsigm(a0[0]) * ftanh(a0[2]);
            const float hn0 = fsigm(a0[3]) * ftanh(cn0);
            const float cn1 = fsigm(a1[1]) * c1 + fsigm(a1[0]) * ftanh(a1[2]);
            const float hn1 = fsigm(a1[3]) * ftanh(cn1);
            c0 = cn0; c1 = cn1;
            Hsb[((size_t)mc * TT + t) * HH + p * UPB + uc0] = f2bf(hn0);
            Hsb[((size_t)mc * TT + t) * HH + p * UPB + uc1] = f2bf(hn1);
            float* hb = hbuf + ((size_t)((t + 1) & 1) * BB + mc) * HH + p * UPB;
            hb[uc0] = hn0;
            hb[uc1] = hn1;
        }
        __syncthreads();   // compiler drains vmcnt(0) before s_barrier => all stores in L2
        if (tid == 0) {
            __threadfence();   // release
            __hip_atomic_fetch_add(cnt, 1, __ATOMIC_RELAXED, __HIP_MEMORY_SCOPE_AGENT);
        }
    }
}

// ---------------- Stage D: MFMA bf16 GEMM: out[m][v] = Hsb[m,:] . Woutb[v,:] + bout[v] ----------------
__global__ __launch_bounds__(256, 2) void stage_logits_mfma(const unsigned short* __restrict__ A,
                                                            const unsigned short* __restrict__ Bm,
                                                            const float* __restrict__ bout,
                                                            float* __restrict__ out) {
    __shared__ unsigned short As[128][40];
    __shared__ unsigned short Bs[128][40];
    const int tid = threadIdx.x;
    const int m0 = blockIdx.y * 128;
    const int n0 = blockIdx.x * 128;
    const int w = tid >> 6, l = tid & 63;
    const int wr = w >> 1, wc = w & 1;
    const int lr = l & 15, lk = l >> 4;

    f32x4 acc[4][4] = {};
    for (int k0 = 0; k0 < HH; k0 += 32) {
#pragma unroll
        for (int i = 0; i < 2; ++i) {
            const int uidx = tid + 256 * i;
            const int rr = uidx >> 2, ss = uidx & 3;
            *(uint4*)&As[rr][ss * 8] = *(const uint4*)(A + (size_t)(m0 + rr) * HH + k0 + ss * 8);
            *(uint4*)&Bs[rr][ss * 8] = *(const uint4*)(Bm + (size_t)(n0 + rr) * HH + k0 + ss * 8);
        }
        __syncthreads();
        bf16x8v af[4], bfr[4];
#pragma unroll
        for (int f = 0; f < 4; ++f) {
            af[f]  = *(const bf16x8v*)&As[wr * 64 + f * 16 + lr][lk * 8];
            bfr[f] = *(const bf16x8v*)&Bs[wc * 64 + f * 16 + lr][lk * 8];
        }
#pragma unroll
        for (int fm = 0; fm < 4; ++fm)
#pragma unroll
            for (int fn = 0; fn < 4; ++fn)
                acc[fm][fn] = __builtin_amdgcn_mfma_f32_16x16x32_bf16(af[fm], bfr[fn], acc[fm][fn], 0, 0, 0);
        __syncthreads();
    }
#pragma unroll
    for (int fn = 0; fn < 4; ++fn) {
        const int n = n0 + wc * 64 + fn * 16 + lr;
        const float bv = bout[n];
#pragma unroll
        for (int fm = 0; fm < 4; ++fm) {
            const int mbase = m0 + wr * 64 + fm * 16 + lk * 4;
#pragma unroll
            for (int rg = 0; rg < 4; ++rg)
                out[(size_t)(mbase + rg) * VV + n] = acc[fm][fn][rg] + bv;
        }
    }
}

// ---------------- Stage E: in-place log_softmax over V per row ----------------
__global__ __launch_bounds__(256) void stage_lsm(float* __restrict__ out) {
    __shared__ float buf[VV];
    __shared__ float red[16];
    const size_t m = blockIdx.x;
    float4* row4 = (float4*)(out + m * VV);
    float4* buf4 = (float4*)buf;
    const int tid = threadIdx.x;

    float mx = -INFINITY;
    for (int k4 = tid; k4 < VV / 4; k4 += 256) {
        const float4 v = row4[k4];
        buf4[k4] = v;
        mx = fmaxf(mx, fmaxf(fmaxf(v.x, v.y), fmaxf(v.z, v.w)));
    }
#pragma unroll
    for (int off = 32; off > 0; off >>= 1) mx = fmaxf(mx, __shfl_down(mx, off, 64));
    if ((tid & 63) == 0) red[tid >> 6] = mx;
    __syncthreads();
    if (tid == 0) {
        float m2 = red[0];
        for (int i = 1; i < 4; ++i) m2 = fmaxf(m2, red[i]);
        red[0] = m2;
    }
    __syncthreads();
    mx = red[0];

    float s = 0.f;
    for (int k4 = tid; k4 < VV / 4; k4 += 256) {
        const float4 v = buf4[k4];
        s += fexp(v.x - mx) + fexp(v.y - mx) + fexp(v.z - mx) + fexp(v.w - mx);
    }
#pragma unroll
    for (int off = 32; off > 0; off >>= 1) s += __shfl_down(s, off, 64);
    if ((tid & 63) == 0) red[8 + (tid >> 6)] = s;
    __syncthreads();
    if (tid == 0) {
        float s2 = 0.f;
        for (int i = 0; i < 4; ++i) s2 += red[8 + i];
        red[8] = logf(s2);
    }
    __syncthreads();
    const float lse = mx + red[8];
    for (int k4 = tid; k4 < VV / 4; k4 += 256) {
        float4 v = buf4[k4];
        v.x -= lse; v.y -= lse; v.z -= lse; v.w -= lse;
        row4[k4] = v;
    }
}

extern "C" void kernel_launch(void* const* d_in, const int* in_sizes, int n_in,
                              void* d_out, int out_size, void* d_ws, size_t ws_size,
                              hipStream_t stream) {
    const float* ac   = (const float*)d_in[0];
    const int*   tok  = (const int*)d_in[1];
    const float* emb  = (const float*)d_in[2];
    const float* Win  = (const float*)d_in[3];
    const float* bin  = (const float*)d_in[4];
    const float* Wih  = (const float*)d_in[5];
    const float* Whh  = (const float*)d_in[6];
    const float* bih  = (const float*)d_in[7];
    const float* bhh  = (const float*)d_in[8];
    const float* Wout = (const float*)d_in[9];
    const float* bout = (const float*)d_in[10];
    float* out = (float*)d_out;

    float* X  = (float*)d_ws;                                   // [T*B,H] fp32, 21 MB
    float* Gp = X + (size_t)TT * BB * HH;                       // [T][8][4][40][32], 80 MB
    unsigned short* Hsb   = (unsigned short*)(Gp + (size_t)TT * BB * G4);  // [B*T][H] bf16
    unsigned short* Woutb = Hsb + (size_t)TT * BB * HH;         // [V][H] bf16
    float* hbuf = (float*)(Woutb + (size_t)VV * HH);            // [2][BB][HH]
    int*   cnt  = (int*)(hbuf + 2 * BB * HH);

    stage_x<<<dim3(TT * BB / 8), dim3(320), 0, stream>>>(ac, tok, emb, Win, bin, X);
    stage_gin<<<dim3(TT * BB / 8), dim3(256), 0, stream>>>(X, Wih, bih, bhh, Gp);
    wcvt<<<dim3((VV * HH / 4 + 255) / 256), dim3(256), 0, stream>>>(Wout, Woutb, VV * HH / 4);
    hipMemsetAsync(cnt, 0, 64, stream);
    stage_rec<<<dim3(64), dim3(RTHR), 0, stream>>>(Gp, Whh, Hsb, hbuf, cnt);
    stage_logits_mfma<<<dim3(VV / 128, TT * BB / 128), dim3(256), 0, stream>>>(Hsb, Woutb, bout, out);
    stage_lsm<<<dim3(TT * BB), dim3(256), 0, stream>>>(out);
}